// Round 1
// baseline (187.714 us; speedup 1.0000x reference)
//
#include <hip/hip_runtime.h>

#define NL 128          // N_LABELS
#define TT 512          // T
#define NB 512          // B
#define START_IDX 126
#define STOP_IDX 127

typedef __attribute__((ext_vector_type(8))) short bf16x8;
typedef __attribute__((ext_vector_type(4))) float f32x4;

__device__ __forceinline__ short f2bf(float x) {
    union { float f; unsigned u; } v; v.f = x;
    unsigned r = (v.u + 0x7FFFu + ((v.u >> 16) & 1u)) >> 16;  // RNE
    return (short)r;
}

// One block per batch. 4 waves; wave w owns labels [32w, 32w+32) as two 16-col
// MFMA N-tiles. B-operand = exp(trans)^T kept in registers (constant over t).
// v (exp-space alpha) round-trips through a 512B LDS double buffer as the
// A-operand; all 16 rows of A are duplicates of v, so row 0 of the C-frag is
// the GEMV result and all LDS reads are broadcasts (conflict-free).
__global__ __launch_bounds__(256, 2)
void crf_fwd_kernel(const float* __restrict__ logits,
                    const int* __restrict__ lens,
                    const float* __restrict__ trans,
                    float* __restrict__ out)
{
    const int b    = blockIdx.x;
    const int tid  = threadIdx.x;
    const int wave = tid >> 6;
    const int lane = tid & 63;
    const int col  = lane & 15;
    const int kgrp = lane >> 4;          // 0..3 -> k-slice (8 consecutive k)

    __shared__ __align__(16) short Vbuf[2][NL];
    __shared__ float red[4];

    // ---- B fragments: B[k][label] = exp(trans[label][k]) ----
    bf16x8 bfrag[2][4];                  // [n-tile][k-step]
    #pragma unroll
    for (int n = 0; n < 2; ++n) {
        const int label = wave * 32 + n * 16 + col;
        #pragma unroll
        for (int kk = 0; kk < 4; ++kk) {
            const float* tp = trans + label * NL + kk * 32 + kgrp * 8;
            bf16x8 f;
            #pragma unroll
            for (int m = 0; m < 8; ++m) f[m] = f2bf(__expf(tp[m]));
            bfrag[n][kk] = f;
        }
    }
    const int lbl0 = wave * 32 + col;
    const int lbl1 = lbl0 + 16;
    const float ets0 = __expf(trans[STOP_IDX * NL + lbl0]);
    const float ets1 = __expf(trans[STOP_IDX * NL + lbl1]);

    int len = lens[b];
    len = len < 1 ? 1 : (len > TT ? TT : len);

    // v0 = one-hot at START (bf16 1.0 = 0x3F80)
    if (tid < NL) Vbuf[0][tid] = (tid == START_IDX) ? (short)0x3F80 : (short)0;

    const float* lg = logits + (size_t)b * (TT * NL);
    float l0 = lg[lbl0];                 // prefetched logits for t=0
    float l1 = lg[lbl1];
    float c  = 0.f;                      // log-scale accumulator (uniform)
    float nv0 = 0.f, nv1 = 0.f;          // this wave's v for lbl0/lbl1

    __syncthreads();

    for (int t = 0; t < len; ++t) {
        const short* vb = Vbuf[t & 1];
        // prefetch next-step logits (clamped on last iter)
        const int tn = (t + 1 < len) ? t + 1 : t;
        const float pl0 = lg[tn * NL + lbl0];
        const float pl1 = lg[tn * NL + lbl1];

        f32x4 acc0 = {0.f, 0.f, 0.f, 0.f};
        f32x4 acc1 = {0.f, 0.f, 0.f, 0.f};
        #pragma unroll
        for (int kk = 0; kk < 4; ++kk) {
            bf16x8 af = *(const bf16x8*)(vb + kk * 32 + kgrp * 8);  // broadcast
            acc0 = __builtin_amdgcn_mfma_f32_16x16x32_bf16(af, bfrag[0][kk], acc0, 0, 0, 0);
            acc1 = __builtin_amdgcn_mfma_f32_16x16x32_bf16(af, bfrag[1][kk], acc1, 0, 0, 0);
        }

        nv0 = acc0[0] * __expf(l0);      // v' = (ET·v) * exp(logit)
        nv1 = acc1[0] * __expf(l1);

        if ((t & 3) == 3) {              // exact power-of-2 rescale
            float m = fmaxf(nv0, nv1);
            m = fmaxf(m, __shfl_xor(m, 1));
            m = fmaxf(m, __shfl_xor(m, 2));
            m = fmaxf(m, __shfl_xor(m, 4));
            m = fmaxf(m, __shfl_xor(m, 8));
            if (lane == 0) red[wave] = m;
            __syncthreads();
            m = fmaxf(fmaxf(red[0], red[1]), fmaxf(red[2], red[3]));
            union { float f; unsigned u; } mu; mu.f = m;
            const int eb = (int)(mu.u >> 23);                 // biased exponent
            union { float f; unsigned u; } sc;
            sc.u = (unsigned)(253 - eb) << 23;                // 2^(126-eb)
            nv0 *= sc.f; nv1 *= sc.f;
            c += (float)(eb - 126) * 0.69314718055994531f;
        }

        if (lane < 16) {                 // publish v' for next step
            short* vw = Vbuf[(t + 1) & 1];
            vw[lbl0] = f2bf(nv0);
            vw[lbl1] = f2bf(nv1);
        }
        l0 = pl0; l1 = pl1;
        __syncthreads();
    }

    // out[b] = c + log( sum_i v[i] * exp(trans[STOP][i]) )
    float p = nv0 * ets0 + nv1 * ets1;
    p += __shfl_xor(p, 1);
    p += __shfl_xor(p, 2);
    p += __shfl_xor(p, 4);
    p += __shfl_xor(p, 8);
    if (lane == 0) red[wave] = p;
    __syncthreads();
    if (tid == 0) out[b] = c + __logf(red[0] + red[1] + red[2] + red[3]);
}

extern "C" void kernel_launch(void* const* d_in, const int* in_sizes, int n_in,
                              void* d_out, int out_size, void* d_ws, size_t ws_size,
                              hipStream_t stream) {
    const float* logits = (const float*)d_in[0];
    const int*   lens   = (const int*)d_in[1];
    const float* trans  = (const float*)d_in[2];
    float*       outp   = (float*)d_out;
    crf_fwd_kernel<<<NB, 256, 0, stream>>>(logits, lens, trans, outp);
}